// Round 2
// baseline (193.782 us; speedup 1.0000x reference)
//
#include <hip/hip_runtime.h>

// OpeningLoss2D: grey_opening(x, size=2) per 2D map, then mean((x - open)^2).
// size=2 -> erosion offsets [-1,0], dilation offsets [0,+1]; symmetric pad of
// width 1 == edge clamp. Separable min/max streamed through registers.
// Shuffle-free: column neighbors come from 2 extra dword loads (L1 hits),
// removing the ds_permute latency from the row-to-row rolling chain.

constexpr int W = 512;
constexpr int H = 512;
constexpr int RPW = 16;                 // rows per wave strip
constexpr int STRIPS = H / RPW;         // 32

__global__ __launch_bounds__(256) void open_loss(
    const float* __restrict__ x, float* __restrict__ out, float invN) {
  const int gtid = blockIdx.x * blockDim.x + threadIdx.x;
  const int wave = gtid >> 6;
  const int lane = threadIdx.x & 63;
  const int img = wave >> 5;            // / STRIPS
  const int strip = wave & (STRIPS - 1);

  // lane's 8 columns of row rs
  const float* base =
      x + ((size_t)img * H + (size_t)strip * RPW) * W + (size_t)lane * 8;

  float v[8], cm[8], cm8;               // current row: x, col-min, boundary col-min
  float pcm[8], pcm8;                   // previous row col-min
  float xp[8], dmp[8];                  // x and dilation-row-max of row being finished
  const int loff = (lane == 0) ? 0 : -1;    // col -1 clamps to 0
  const int roff = (lane == 63) ? 7 : 8;    // col 512 clamps to 511

  // load row (drow relative to rs) and compute its column mins
  auto loadrow = [&](int drow) {
    const float* p = base + (ptrdiff_t)drow * W;
    float4 a = *reinterpret_cast<const float4*>(p);
    float4 b = *reinterpret_cast<const float4*>(p + 4);
    v[0] = a.x; v[1] = a.y; v[2] = a.z; v[3] = a.w;
    v[4] = b.x; v[5] = b.y; v[6] = b.z; v[7] = b.w;
    const float left = p[loff];
    const float right = p[roff];
    cm[0] = fminf(left, v[0]);
#pragma unroll
    for (int k = 1; k < 8; ++k) cm[k] = fminf(v[k - 1], v[k]);
    cm8 = fminf(v[7], right);
  };

  // --- prologue: row rs-1 (clamped) -> pcm ---
  loadrow(strip ? -1 : 0);
#pragma unroll
  for (int k = 0; k < 8; ++k) pcm[k] = cm[k];
  pcm8 = cm8;

  // --- row rs: erosion + its dilation row-max -> dmp ---
  loadrow(0);
  {
    float er[8];
#pragma unroll
    for (int k = 0; k < 8; ++k) er[k] = fminf(pcm[k], cm[k]);
    const float er8 = fminf(pcm8, cm8);
#pragma unroll
    for (int k = 0; k < 7; ++k) dmp[k] = fmaxf(er[k], er[k + 1]);
    dmp[7] = fmaxf(er[7], er8);
#pragma unroll
    for (int k = 0; k < 8; ++k) { xp[k] = v[k]; pcm[k] = cm[k]; }
    pcm8 = cm8;
  }

  float acc = 0.f;

  // finish row i using row i+1 (= rs + drow_next)
  auto advance = [&](int drow_next) {
    loadrow(drow_next);
    float er[8], dmn[8];
#pragma unroll
    for (int k = 0; k < 8; ++k) er[k] = fminf(pcm[k], cm[k]);
    const float er8 = fminf(pcm8, cm8);
#pragma unroll
    for (int k = 0; k < 7; ++k) dmn[k] = fmaxf(er[k], er[k + 1]);
    dmn[7] = fmaxf(er[7], er8);
#pragma unroll
    for (int k = 0; k < 8; ++k) {
      const float d = xp[k] - fmaxf(dmp[k], dmn[k]);
      acc = fmaf(d, d, acc);
      xp[k] = v[k]; pcm[k] = cm[k]; dmp[k] = dmn[k];
    }
    pcm8 = cm8;
  };

  // rows rs .. rs+14: next row always in-bounds (rs+15 <= 511)
#pragma unroll 5
  for (int r = 1; r <= RPW - 1; ++r) advance(r);

  // row rs+15: next row is rs+16, in-bounds except for the last strip
  if (strip != STRIPS - 1) {
    advance(RPW);
  } else {  // row 511: dilation's row 512 clamps to row 511 -> di = dmp
#pragma unroll
    for (int k = 0; k < 8; ++k) {
      const float d = xp[k] - dmp[k];
      acc = fmaf(d, d, acc);
    }
  }

  // wave reduce (64 lanes) -> block reduce -> one atomic per block
#pragma unroll
  for (int off = 32; off > 0; off >>= 1) acc += __shfl_down(acc, off);
  __shared__ float sh[4];
  const int wid = threadIdx.x >> 6;
  if (lane == 0) sh[wid] = acc;
  __syncthreads();
  if (threadIdx.x == 0) {
    atomicAdd(out, (sh[0] + sh[1] + sh[2] + sh[3]) * invN);
  }
}

extern "C" void kernel_launch(void* const* d_in, const int* in_sizes, int n_in,
                              void* d_out, int out_size, void* d_ws, size_t ws_size,
                              hipStream_t stream) {
  const float* x = (const float*)d_in[0];
  float* out = (float*)d_out;

  const long long n = in_sizes[0];                 // 16*8*512*512 = 2^25
  const int nImg = (int)(n / ((long long)H * W));  // 128
  const int nWaves = nImg * STRIPS;                // 4096
  const int nBlocks = nWaves / 4;                  // 1024 blocks x 256 thr

  const float invN = 1.0f / (float)n;              // 2^-25, exact

  hipMemsetAsync(out, 0, sizeof(float), stream);   // d_out is poisoned 0xAA
  open_loss<<<nBlocks, 256, 0, stream>>>(x, out, invN);
}